// Round 5
// baseline (1228.676 us; speedup 1.0000x reference)
//
#include <hip/hip_runtime.h>

typedef unsigned short u16;
typedef short s16x8 __attribute__((ext_vector_type(8)));
typedef float f32x4 __attribute__((ext_vector_type(4)));
typedef unsigned short u16x8 __attribute__((ext_vector_type(8)));

#define B_   8
#define N_   24000
#define M_   6000
#define K_   32
#define CIN  64
#define CMID 128
#define COUT 256
#define KP1  96     // 67 zero-padded to 3x32 for MFMA K-steps
#define QB16_ 375   // M/16 query-items per (batch, quarter) combo (exact)
#define GRID_ 1024  // 4 blocks/CU x 256 CU — guaranteed co-resident
#define NPH_  4     // phases; phase p owns combos {p*8 + xcd}

// Static device globals — no ws_size assumption, graph-capture safe,
// fully rewritten on every call. Weights in MFMA fragment order.
__device__ __align__(16) u16 g_W1f[CMID * KP1];                 // 24.6 KB bf16
__device__ __align__(16) u16 g_W2f[COUT * CMID];                // 65.5 KB bf16
__device__ __align__(16) u16 g_Yf[(size_t)B_ * N_ * COUT];      // 98.3 MB bf16
__device__ int g_ctr[NPH_ * 8];    // per-(phase,XCD) ticket counters
__device__ int g_bar;              // barrier arrival counter
__device__ int g_go[NPH_];         // one-shot phase release flags

__device__ __forceinline__ float bf2f(u16 u) {
    return __uint_as_float(((unsigned)u) << 16);
}
__device__ __forceinline__ u16 f2bf(float f) {  // fp32 -> bf16 RNE
    unsigned u = __float_as_uint(f);
    u += 0x7FFFu + ((u >> 16) & 1u);
    return (u16)(u >> 16);
}

// ---------------------------------------------------------------------------
// Kernel 0: convert fp32 weights to bf16 in fragment order; zero the
// ticket counters + barrier state for this call (stream-ordered).
// ---------------------------------------------------------------------------
__global__ void prep_weights(const float* __restrict__ W1,
                             const float* __restrict__ W2) {
    if (blockIdx.x == 0) {
        if (threadIdx.x < NPH_ * 8) g_ctr[threadIdx.x] = 0;
        else if (threadIdx.x == NPH_ * 8) g_bar = 0;
        else if (threadIdx.x < NPH_ * 8 + 1 + NPH_)
            g_go[threadIdx.x - (NPH_ * 8 + 1)] = 0;
    }
    int t = blockIdx.x * 256 + threadIdx.x;   // 0..45055
    if (t < CMID * KP1) {                     // 12288 -> W1f
        int blk = t >> 9, off = t & 511;
        int L = off >> 3, j = off & 7;
        int ln = L & 15, quad = L >> 4;
        int w = blk / 6, r = blk % 6;
        int k0i = r >> 1, mt = r & 1;
        int row = w * 32 + mt * 16 + ln;
        int col = k0i * 32 + quad * 8 + j;
        g_W1f[t] = (col < 67) ? f2bf(W1[row * 67 + col]) : (u16)0;
    } else {                                  // 32768 -> W2f
        int i = t - CMID * KP1;
        int blk = i >> 9, off = i & 511;
        int L = off >> 3, j = off & 7;
        int ln = L & 15, quad = L >> 4;
        int w = blk >> 4, r = blk & 15;
        int k0i = r >> 2, mt = r & 3;
        int row = w * 64 + mt * 16 + ln;
        int col = k0i * 32 + quad * 8 + j;
        g_W2f[i] = f2bf(W2[row * 128 + col]);
    }
}

// ---------------------------------------------------------------------------
// Kernel 1: fused conv1+relu+conv2+relu (BYTE-IDENTICAL — once gather
// drops below it, its counters surface in the top-5 for a theory-led edit).
// ---------------------------------------------------------------------------
__global__ __launch_bounds__(256) void conv_fused(
        const float* __restrict__ feat, const float* __restrict__ xyz,
        const float* __restrict__ b1,  const float* __restrict__ b2) {
    __shared__ __align__(16) u16 sm[16896];
    u16* Xs = sm;
    u16* Hs = sm + 6656;
    u16* Ys = sm;

    const int tid  = threadIdx.x;
    const int b    = blockIdx.y;
    const int n0   = blockIdx.x * 64;
    const int w    = tid >> 6;
    const int L    = tid & 63;
    const int ln   = L & 15;
    const int quad = L >> 4;

    if (tid < 64) {
        uint4 z; z.x = z.y = z.z = z.w = 0u;
        u16* xr = Xs + tid * 104;
        *(uint4*)(xr + 64) = z; *(uint4*)(xr + 72) = z;
        *(uint4*)(xr + 80) = z; *(uint4*)(xr + 88) = z;
        const float* s = xyz + (size_t)(b * N_ + n0 + tid) * 3;
        xr[64] = f2bf(s[0]); xr[65] = f2bf(s[1]); xr[66] = f2bf(s[2]);
    }
#pragma unroll
    for (int it = 0; it < 4; ++it) {
        int idx = it * 256 + tid;
        int c   = idx >> 4;
        int p0  = (idx & 15) << 2;
        float4 v = *(const float4*)(feat + (size_t)(b * CIN + c) * N_ + n0 + p0);
        u16* dst = Xs + p0 * 104 + c;
        dst[0]   = f2bf(v.x);
        dst[104] = f2bf(v.y);
        dst[208] = f2bf(v.z);
        dst[312] = f2bf(v.w);
    }
    __syncthreads();

    f32x4 acc1[2][4];
#pragma unroll
    for (int mt = 0; mt < 2; ++mt)
#pragma unroll
        for (int nt = 0; nt < 4; ++nt) {
            f32x4 zz = {0.f, 0.f, 0.f, 0.f};
            acc1[mt][nt] = zz;
        }
#pragma unroll
    for (int k0i = 0; k0i < 3; ++k0i) {
        s16x8 af[2], xf[4];
#pragma unroll
        for (int mt = 0; mt < 2; ++mt)
            af[mt] = *(const s16x8*)(g_W1f + (((w * 3 + k0i) * 2 + mt) << 9) + L * 8);
#pragma unroll
        for (int nt = 0; nt < 4; ++nt)
            xf[nt] = *(const s16x8*)(Xs + (nt * 16 + ln) * 104 + k0i * 32 + quad * 8);
#pragma unroll
        for (int mt = 0; mt < 2; ++mt)
#pragma unroll
            for (int nt = 0; nt < 4; ++nt)
                acc1[mt][nt] = __builtin_amdgcn_mfma_f32_16x16x32_bf16(
                    af[mt], xf[nt], acc1[mt][nt], 0, 0, 0);
    }
#pragma unroll
    for (int mt = 0; mt < 2; ++mt) {
        int m0 = w * 32 + mt * 16 + quad * 4;
        float4 bv = *(const float4*)(b1 + m0);
#pragma unroll
        for (int nt = 0; nt < 4; ++nt) {
            int p = nt * 16 + ln;
            float x0 = acc1[mt][nt][0] + bv.x;
            float x1 = acc1[mt][nt][1] + bv.y;
            float x2 = acc1[mt][nt][2] + bv.z;
            float x3 = acc1[mt][nt][3] + bv.w;
            ushort4 hv;
            hv.x = f2bf(x0 > 0.f ? x0 : 0.f);
            hv.y = f2bf(x1 > 0.f ? x1 : 0.f);
            hv.z = f2bf(x2 > 0.f ? x2 : 0.f);
            hv.w = f2bf(x3 > 0.f ? x3 : 0.f);
            *(ushort4*)(Hs + p * 136 + m0) = hv;
        }
    }
    __syncthreads();

    f32x4 acc2[4][4];
#pragma unroll
    for (int mt = 0; mt < 4; ++mt)
#pragma unroll
        for (int nt = 0; nt < 4; ++nt) {
            f32x4 zz = {0.f, 0.f, 0.f, 0.f};
            acc2[mt][nt] = zz;
        }
#pragma unroll
    for (int k0i = 0; k0i < 4; ++k0i) {
        s16x8 af[4], hf[4];
#pragma unroll
        for (int mt = 0; mt < 4; ++mt)
            af[mt] = *(const s16x8*)(g_W2f + (((w * 4 + k0i) * 4 + mt) << 9) + L * 8);
#pragma unroll
        for (int nt = 0; nt < 4; ++nt)
            hf[nt] = *(const s16x8*)(Hs + (nt * 16 + ln) * 136 + k0i * 32 + quad * 8);
#pragma unroll
        for (int mt = 0; mt < 4; ++mt)
#pragma unroll
            for (int nt = 0; nt < 4; ++nt)
                acc2[mt][nt] = __builtin_amdgcn_mfma_f32_16x16x32_bf16(
                    af[mt], hf[nt], acc2[mt][nt], 0, 0, 0);
    }
    __syncthreads();

#pragma unroll
    for (int mt = 0; mt < 4; ++mt) {
        int c0 = w * 64 + mt * 16 + quad * 4;
        float4 bv = *(const float4*)(b2 + c0);
#pragma unroll
        for (int nt = 0; nt < 4; ++nt) {
            int p = nt * 16 + ln;
            float x0 = acc2[mt][nt][0] + bv.x;
            float x1 = acc2[mt][nt][1] + bv.y;
            float x2 = acc2[mt][nt][2] + bv.z;
            float x3 = acc2[mt][nt][3] + bv.w;
            ushort4 yv;
            yv.x = f2bf(x0 > 0.f ? x0 : 0.f);
            yv.y = f2bf(x1 > 0.f ? x1 : 0.f);
            yv.z = f2bf(x2 > 0.f ? x2 : 0.f);
            yv.w = f2bf(x3 > 0.f ? x3 : 0.f);
            *(ushort4*)(Ys + p * 264 + c0) = yv;
        }
    }
    __syncthreads();

    u16* dstY = g_Yf + ((size_t)b * N_ + n0) * COUT;
#pragma unroll
    for (int i = 0; i < 8; ++i) {
        int g = i * 256 + tid;
        int p = g >> 5, c16 = g & 31;
        *(uint4*)(dstY + (size_t)p * COUT + c16 * 8) =
            *(const uint4*)(Ys + p * 264 + c16 * 8);
    }
}

// ---------------------------------------------------------------------------
// Kernel 2: gather + max, BARRIER-PHASED persistent version.
// R12 post-mortem: measured-XCD ticket queues fixed the SPATIAL mapping but
// FETCH stayed 362 MB — temporal straddle remains: ~150 resident blocks/XCD
// vs 188-ticket combos means the in-flight window covers a combo boundary
// ~80% of the time (2 slabs = 6.1 MB > 4 MB L2). Claim order != completion
// order; nothing ever FORCED combo c to finish before c+1 started.
// Fix: device-wide spin barrier between 4 phases (phase p = combos {p*8+x}).
// Grid = 1024 = 4 blocks/CU guaranteed co-resident (launch_bounds(256,4)
// caps VGPR<=128 -> 16 waves/CU; LDS 12.8 KB -> capacity >=12/CU), so the
// spin barrier cannot deadlock. Items shrink to 16 queries (M=6000=375x16
// exact): 375 items/queue vs ~128 blocks/XCD -> phase tail ~2% (at 32-query
// granularity the ceil(188/128)=2-round tail would cost ~35%). Blocks claim
// from their MEASURED XCC_ID's queue; steal round-robin when drained
// (coverage under any mapping; every item claimed exactly once). Barrier
// state zeroed by prep_weights each call; a stale-flag rocprof replay just
// falls through (no hang). 8-deep MLP (2 rows x 4 k-loads in flight).
// Cross-round fit dur ~ 45us + 0.2us/MB x FETCH predicts: FETCH -> ~140 MB,
// dur -> ~75 us. Max in u16 domain (post-ReLU bf16) = exact bf16 max.
// ---------------------------------------------------------------------------
__global__ __launch_bounds__(256, 4) void gather_max(
        const int* __restrict__ nbr, float* __restrict__ out) {
    __shared__ __align__(16) u16 smem[16 * 400];   // 12.8 KB union
    int* sidx = (int*)smem;                        // [512] ints (2 KB, aliased)
    u16* ymax = smem;                              // [16*400] post-gather
    __shared__ int s_item;

    const int tid = threadIdx.x;
    unsigned xcd = 0;
    if (tid == 0) {
        unsigned xcc;
        asm volatile("s_getreg_b32 %0, hwreg(HW_REG_XCC_ID)" : "=s"(xcc));
        xcd = xcc & 7u;
    }

    const int w  = tid >> 6;         // wave 0..3
    const int L  = tid & 63;
    const int kg = L >> 3;           // k-group 0..7 (neighbor within round)
    const int co = L & 7;            // channel octet within quarter

    for (int p = 0; p < NPH_; ++p) {
        for (;;) {
            // claim one (qx, qb) item for phase p; -1 when phase drained
            if (tid == 0) {
                int item = -1;
                for (int probe = 0; probe < 8; ++probe) {
                    int qx = (int)((xcd + (unsigned)probe) & 7u);
                    int* ctr = &g_ctr[p * 8 + qx];
                    if (__hip_atomic_load(ctr, __ATOMIC_RELAXED,
                                          __HIP_MEMORY_SCOPE_AGENT) >= QB16_)
                        continue;
                    int t = __hip_atomic_fetch_add(ctr, 1, __ATOMIC_RELAXED,
                                                   __HIP_MEMORY_SCOPE_AGENT);
                    if (t < QB16_) { item = qx * QB16_ + t; break; }
                }
                s_item = item;
            }
            __syncthreads();   // broadcasts s_item; also fences smem reuse
            const int item = s_item;
            if (item < 0) break;

            const int qx = item / QB16_;
            const int qb = item % QB16_;
            const int combo = p * 8 + qx;    // 0..31
            const int b  = combo >> 2;
            const int q  = combo & 3;        // channel quarter (64 ch)
            const int m0 = qb * 16;

            // stage neighbor indices: 16 queries x 32 k (always full item)
            if (tid < 128)
                *(int4*)(sidx + tid * 4) =
                    *(const int4*)(nbr + ((size_t)b * M_ + m0) * K_ + tid * 4);
            __syncthreads();

            const u16* base = g_Yf + (size_t)b * N_ * COUT + q * 64 + co * 8;

            u16x8 mx[4];
#pragma unroll
            for (int h = 0; h < 2; ++h) {    // 8-deep MLP: 2 rows x 4 loads
                int id[8];
#pragma unroll
                for (int s = 0; s < 2; ++s) {
                    int ml = (w << 2) + (h << 1) + s;
#pragma unroll
                    for (int r = 0; r < 4; ++r)
                        id[s * 4 + r] = sidx[ml * K_ + r * 8 + kg];
                }
                u16x8 v[8];
#pragma unroll
                for (int jj = 0; jj < 8; ++jj) {
                    unsigned u = (unsigned)id[jj];
                    u = u < (unsigned)N_ ? u : 0u;   // defensive clamp
                    v[jj] = *(const u16x8*)(base + (size_t)u * COUT);
                }
#pragma unroll
                for (int s = 0; s < 2; ++s) {
                    u16x8 a = __builtin_elementwise_max(v[s*4+0], v[s*4+1]);
                    u16x8 c = __builtin_elementwise_max(v[s*4+2], v[s*4+3]);
                    mx[h * 2 + s] = __builtin_elementwise_max(a, c);
                }
            }
            __syncthreads();   // sidx reads done; ymax aliases that storage

            // reduce across the 8 k-groups (lane bits 3,4,5)
#pragma unroll
            for (int i = 0; i < 4; ++i) {
                u16x8 m8 = mx[i];
#pragma unroll
                for (int mask = 8; mask <= 32; mask <<= 1) {
                    int4 t = *(int4*)&m8;
                    t.x = __shfl_xor(t.x, mask);
                    t.y = __shfl_xor(t.y, mask);
                    t.z = __shfl_xor(t.z, mask);
                    t.w = __shfl_xor(t.w, mask);
                    m8 = __builtin_elementwise_max(m8, *(u16x8*)&t);
                }
                if (kg == 0)   // one replicate writes 8 channels, 16B ds_write
                    *(u16x8*)(ymax + ((w << 2) + i) * 400 + co * 8) = m8;
            }
            __syncthreads();

            // transpose + bf16->fp32: out[b][q*64+c][m0..m0+15]
            {
                int c  = tid >> 2;           // local channel 0..63
                int mc = (tid & 3) << 2;     // 0,4,8,12
                float4 v;
                v.x = bf2f(ymax[(mc + 0) * 400 + c]);
                v.y = bf2f(ymax[(mc + 1) * 400 + c]);
                v.z = bf2f(ymax[(mc + 2) * 400 + c]);
                v.w = bf2f(ymax[(mc + 3) * 400 + c]);
                *(float4*)(out + (size_t)(b * COUT + q * 64 + c) * M_ + m0 + mc) = v;
            }
            // loop: next claim's __syncthreads covers the ymax read hazard
        }

        // device-wide phase barrier (skip after last phase)
        if (p < NPH_ - 1) {
            if (tid == 0) {
                int v = __hip_atomic_fetch_add(&g_bar, 1, __ATOMIC_ACQ_REL,
                                               __HIP_MEMORY_SCOPE_AGENT);
                if (v == GRID_ - 1) {
                    __hip_atomic_store(&g_bar, 0, __ATOMIC_RELAXED,
                                       __HIP_MEMORY_SCOPE_AGENT);
                    __hip_atomic_store(&g_go[p], 1, __ATOMIC_RELEASE,
                                       __HIP_MEMORY_SCOPE_AGENT);
                } else {
                    while (!__hip_atomic_load(&g_go[p], __ATOMIC_ACQUIRE,
                                              __HIP_MEMORY_SCOPE_AGENT))
                        __builtin_amdgcn_s_sleep(8);
                }
            }
            __syncthreads();
        }
    }
}

extern "C" void kernel_launch(void* const* d_in, const int* in_sizes, int n_in,
                              void* d_out, int out_size, void* d_ws, size_t ws_size,
                              hipStream_t stream) {
    // inputs (all fp32 except neighbor_idx int32):
    // 0=query_xyz(unused) 1=support_xyz 2=features 3=neighbor_idx
    // 4=W1 5=b1 6=W2 7=b2. Output: fp32 [B][C_OUT][M].
    const float* xyz  = (const float*)d_in[1];
    const float* feat = (const float*)d_in[2];
    const int*   nbr  = (const int*)d_in[3];
    const float* W1   = (const float*)d_in[4];
    const float* b1   = (const float*)d_in[5];
    const float* W2   = (const float*)d_in[6];
    const float* b2   = (const float*)d_in[7];
    float* out = (float*)d_out;
    (void)d_ws; (void)ws_size;

    prep_weights<<<176, 256, 0, stream>>>(W1, W2);
    conv_fused<<<dim3(N_ / 64, B_), 256, 0, stream>>>(feat, xyz, b1, b2);
    gather_max<<<GRID_, 256, 0, stream>>>(nbr, out);   // 1024 persistent blocks
}

// Round 6
// 253.215 us; speedup vs baseline: 4.8523x; 4.8523x over previous
//
#include <hip/hip_runtime.h>
#include <hip/hip_bf16.h>

typedef unsigned short u16;
typedef short s16x8 __attribute__((ext_vector_type(8)));
typedef float f32x4 __attribute__((ext_vector_type(4)));
typedef unsigned short u16x8 __attribute__((ext_vector_type(8)));

#define B_   8
#define N_   24000
#define M_   6000
#define K_   32
#define CIN  64
#define CMID 128
#define COUT 256
#define KP1  96    // 67 zero-padded to 3x32 for MFMA K-steps
#define QB_  188   // ceil(M/32) query-blocks per (batch, quarter) combo

// Static device globals — no ws_size assumption, graph-capture safe,
// fully rewritten on every call. Weights in MFMA fragment order.
__device__ __align__(16) u16 g_W1f[CMID * KP1];                 // 24.6 KB bf16
__device__ __align__(16) u16 g_W2f[COUT * CMID];                // 65.5 KB bf16
__device__ __align__(16) u16 g_Yf[(size_t)B_ * N_ * COUT];      // 98.3 MB bf16

__device__ __forceinline__ float bf2f(u16 u) {
    return __uint_as_float(((unsigned)u) << 16);
}
__device__ __forceinline__ u16 f2bf(float f) {  // fp32 -> bf16 RNE (scalar)
    unsigned u = __float_as_uint(f);
    u += 0x7FFFu + ((u >> 16) & 1u);
    return (u16)(u >> 16);
}
// packed fp32 pair -> 2x bf16 (RNE) in one u32; compiler emits
// v_cvt_pk_bf16_f32 (do NOT hand-write asm — m240). Bit-identical to f2bf.
__device__ __forceinline__ unsigned f2bf2(float lo, float hi) {
    __hip_bfloat162 h = __float22bfloat162_rn(make_float2(lo, hi));
    unsigned r;
    __builtin_memcpy(&r, &h, 4);
    return r;   // lo in bits[15:0], hi in bits[31:16]
}

// ---------------------------------------------------------------------------
// Kernel 0: convert fp32 weights to bf16 in fragment order. (unchanged)
// ---------------------------------------------------------------------------
__global__ void prep_weights(const float* __restrict__ W1,
                             const float* __restrict__ W2) {
    int t = blockIdx.x * 256 + threadIdx.x;   // 0..45055
    if (t < CMID * KP1) {                     // 12288 -> W1f
        int blk = t >> 9, off = t & 511;
        int L = off >> 3, j = off & 7;
        int ln = L & 15, quad = L >> 4;
        int w = blk / 6, r = blk % 6;
        int k0i = r >> 1, mt = r & 1;
        int row = w * 32 + mt * 16 + ln;
        int col = k0i * 32 + quad * 8 + j;
        g_W1f[t] = (col < 67) ? f2bf(W1[row * 67 + col]) : (u16)0;
    } else {                                  // 32768 -> W2f
        int i = t - CMID * KP1;
        int blk = i >> 9, off = i & 511;
        int L = off >> 3, j = off & 7;
        int ln = L & 15, quad = L >> 4;
        int w = blk >> 4, r = blk & 15;
        int k0i = r >> 2, mt = r & 3;
        int row = w * 64 + mt * 16 + ln;
        int col = k0i * 32 + quad * 8 + j;
        g_W2f[i] = f2bf(W2[row * 128 + col]);
    }
}

// ---------------------------------------------------------------------------
// Kernel 1: fused conv1+relu+conv2+relu. R13 first conv edit: the hand-rolled
// f2bf (4-5 VALU ops) ran ~48x/thread (staging 16 + two epilogues 32) plus
// branchy ReLU selects — ~250 VALU ops/thread > MFMA's 422 cyc/wave, i.e.
// conv is VALU-bound on CONVERSIONS, not MFMA. Fix: packed v_cvt_pk_bf16_f32
// via __float22bfloat162_rn (RNE, bit-identical) + fmaxf ReLU: epilogue
// 4-value path 28 -> ~10 VALU ops; staging 16 -> ~6. Structure/layout/MFMA
// untouched. Predict conv ~117 -> ~85-95 us.
// ---------------------------------------------------------------------------
__global__ __launch_bounds__(256) void conv_fused(
        const float* __restrict__ feat, const float* __restrict__ xyz,
        const float* __restrict__ b1,  const float* __restrict__ b2) {
    __shared__ __align__(16) u16 sm[16896];
    u16* Xs = sm;
    u16* Hs = sm + 6656;
    u16* Ys = sm;

    const int tid  = threadIdx.x;
    const int b    = blockIdx.y;
    const int n0   = blockIdx.x * 64;
    const int w    = tid >> 6;
    const int L    = tid & 63;
    const int ln   = L & 15;
    const int quad = L >> 4;

    if (tid < 64) {
        uint4 z; z.x = z.y = z.z = z.w = 0u;
        u16* xr = Xs + tid * 104;
        *(uint4*)(xr + 64) = z; *(uint4*)(xr + 72) = z;
        *(uint4*)(xr + 80) = z; *(uint4*)(xr + 88) = z;
        const float* s = xyz + (size_t)(b * N_ + n0 + tid) * 3;
        xr[64] = f2bf(s[0]); xr[65] = f2bf(s[1]); xr[66] = f2bf(s[2]);
    }
#pragma unroll
    for (int it = 0; it < 4; ++it) {
        int idx = it * 256 + tid;
        int c   = idx >> 4;
        int p0  = (idx & 15) << 2;
        float4 v = *(const float4*)(feat + (size_t)(b * CIN + c) * N_ + n0 + p0);
        u16* dst = Xs + p0 * 104 + c;
        unsigned pxy = f2bf2(v.x, v.y);
        unsigned pzw = f2bf2(v.z, v.w);
        dst[0]   = (u16)pxy;
        dst[104] = (u16)(pxy >> 16);
        dst[208] = (u16)pzw;
        dst[312] = (u16)(pzw >> 16);
    }
    __syncthreads();

    f32x4 acc1[2][4];
#pragma unroll
    for (int mt = 0; mt < 2; ++mt)
#pragma unroll
        for (int nt = 0; nt < 4; ++nt) {
            f32x4 zz = {0.f, 0.f, 0.f, 0.f};
            acc1[mt][nt] = zz;
        }
#pragma unroll
    for (int k0i = 0; k0i < 3; ++k0i) {
        s16x8 af[2], xf[4];
#pragma unroll
        for (int mt = 0; mt < 2; ++mt)
            af[mt] = *(const s16x8*)(g_W1f + (((w * 3 + k0i) * 2 + mt) << 9) + L * 8);
#pragma unroll
        for (int nt = 0; nt < 4; ++nt)
            xf[nt] = *(const s16x8*)(Xs + (nt * 16 + ln) * 104 + k0i * 32 + quad * 8);
#pragma unroll
        for (int mt = 0; mt < 2; ++mt)
#pragma unroll
            for (int nt = 0; nt < 4; ++nt)
                acc1[mt][nt] = __builtin_amdgcn_mfma_f32_16x16x32_bf16(
                    af[mt], xf[nt], acc1[mt][nt], 0, 0, 0);
    }
#pragma unroll
    for (int mt = 0; mt < 2; ++mt) {
        int m0 = w * 32 + mt * 16 + quad * 4;
        float4 bv = *(const float4*)(b1 + m0);
#pragma unroll
        for (int nt = 0; nt < 4; ++nt) {
            int p = nt * 16 + ln;
            uint2 hv;
            hv.x = f2bf2(fmaxf(acc1[mt][nt][0] + bv.x, 0.f),
                         fmaxf(acc1[mt][nt][1] + bv.y, 0.f));
            hv.y = f2bf2(fmaxf(acc1[mt][nt][2] + bv.z, 0.f),
                         fmaxf(acc1[mt][nt][3] + bv.w, 0.f));
            *(uint2*)(Hs + p * 136 + m0) = hv;
        }
    }
    __syncthreads();

    f32x4 acc2[4][4];
#pragma unroll
    for (int mt = 0; mt < 4; ++mt)
#pragma unroll
        for (int nt = 0; nt < 4; ++nt) {
            f32x4 zz = {0.f, 0.f, 0.f, 0.f};
            acc2[mt][nt] = zz;
        }
#pragma unroll
    for (int k0i = 0; k0i < 4; ++k0i) {
        s16x8 af[4], hf[4];
#pragma unroll
        for (int mt = 0; mt < 4; ++mt)
            af[mt] = *(const s16x8*)(g_W2f + (((w * 4 + k0i) * 4 + mt) << 9) + L * 8);
#pragma unroll
        for (int nt = 0; nt < 4; ++nt)
            hf[nt] = *(const s16x8*)(Hs + (nt * 16 + ln) * 136 + k0i * 32 + quad * 8);
#pragma unroll
        for (int mt = 0; mt < 4; ++mt)
#pragma unroll
            for (int nt = 0; nt < 4; ++nt)
                acc2[mt][nt] = __builtin_amdgcn_mfma_f32_16x16x32_bf16(
                    af[mt], hf[nt], acc2[mt][nt], 0, 0, 0);
    }
    __syncthreads();

#pragma unroll
    for (int mt = 0; mt < 4; ++mt) {
        int c0 = w * 64 + mt * 16 + quad * 4;
        float4 bv = *(const float4*)(b2 + c0);
#pragma unroll
        for (int nt = 0; nt < 4; ++nt) {
            int p = nt * 16 + ln;
            uint2 yv;
            yv.x = f2bf2(fmaxf(acc2[mt][nt][0] + bv.x, 0.f),
                         fmaxf(acc2[mt][nt][1] + bv.y, 0.f));
            yv.y = f2bf2(fmaxf(acc2[mt][nt][2] + bv.z, 0.f),
                         fmaxf(acc2[mt][nt][3] + bv.w, 0.f));
            *(uint2*)(Ys + p * 264 + c0) = yv;
        }
    }
    __syncthreads();

    u16* dstY = g_Yf + ((size_t)b * N_ + n0) * COUT;
#pragma unroll
    for (int i = 0; i < 8; ++i) {
        int g = i * 256 + tid;
        int p = g >> 5, c16 = g & 31;
        *(uint4*)(dstY + (size_t)p * COUT + c16 * 8) =
            *(const uint4*)(Ys + p * 264 + c16 * 8);
    }
}

// ---------------------------------------------------------------------------
// Kernel 2: gather + max — REVERTED verbatim to the measured-best R2
// bucket-sorted version (107.5 us @ FETCH 305 MB). L2-locality program is
// CLOSED: 5 schemes (swizzle %8, masked 2-phase, sorted 3-phase, persistent
// 4-combo, measured-XCD queues, barrier phases) never pushed FETCH below
// ~277 MB; R5's hard-barrier test proved even a single resident 3.07 MB
// slab (77% of L2) is evicted by streaming write/index traffic. The ~300 MB
// fetch at ~5 TB/s L3->L2 is the operating point; remaining gather levers
// would be issue-rate/MLP, not locality.
// ---------------------------------------------------------------------------
__global__ __launch_bounds__(256) void gather_max(
        const int* __restrict__ nbr, float* __restrict__ out) {
    __shared__ __align__(16) u16 smem[32 * 400];          // 25.6 KB union
    int* sidx  = (int*)smem;                              // [1024] bytes 0..4095
    u16* ssort = smem + 2048;                             // [1024] bytes 4096..6143
    int* soff  = (int*)(smem + 3072);                     // [128]  bytes 6144..6655
    int* scur  = (int*)(smem + 3328);                     // [128]  bytes 6656..7167
    u16* ymax  = smem;                                    // [32*400] post-gather

    const int tid = threadIdx.x;
    const int l   = blockIdx.x;
    const int xcd = l & 7;
    const int j   = l >> 3;          // 0..751
    const int cw  = j / QB_;         // combo-within-XCD 0..3
    const int qb  = j % QB_;         // query-block 0..187
    const int combo = cw * 8 + xcd;  // 0..31
    const int b   = combo >> 2;
    const int q   = combo & 3;       // channel quarter (64 ch)
    const int m0  = qb * 32;
    const int row = tid >> 3;        // row owning this thread's 4 staged ints
    const int Mv0 = M_ - m0;
    const int Mv  = Mv0 < 32 ? Mv0 : 32;   // valid rows this block (16 or 32)

    // stage neighbor indices (32 queries x 32 k) + zero bucket counters
    if (row < Mv)
        *(int4*)(sidx + tid * 4) =
            *(const int4*)(nbr + ((size_t)b * M_ + m0) * K_ + tid * 4);
    if (tid < 128) scur[tid] = 0;
    __syncthreads();

    // pass 1: per-row phase histogram (phases 0,1 only; 2 is implied)
    unsigned uu[4];
#pragma unroll
    for (int jj = 0; jj < 4; ++jj) {
        unsigned u = (unsigned)sidx[tid * 4 + jj];
        u = u < (unsigned)N_ ? u : 0u;     // defensive clamp (also garbage rows)
        uu[jj] = u;
        int p = (int)(u >> 13);            // 0:[0,8192) 1:[8192,16384) 2:rest
        if (p < 2) atomicAdd(&scur[row * 4 + p], 1);
    }
    __syncthreads();

    // prefix: bucket offsets; reset cursors to bucket starts
    if (tid < 32) {
        int c0 = scur[tid * 4 + 0], c1 = scur[tid * 4 + 1];
        soff[tid * 4 + 0] = 0;
        soff[tid * 4 + 1] = c0;
        soff[tid * 4 + 2] = c0 + c1;
        soff[tid * 4 + 3] = 32;
        scur[tid * 4 + 0] = 0;
        scur[tid * 4 + 1] = c0;
        scur[tid * 4 + 2] = c0 + c1;
    }
    __syncthreads();

    // pass 2: place indices into phase buckets (order within bucket arbitrary)
#pragma unroll
    for (int jj = 0; jj < 4; ++jj) {
        int p = (int)(uu[jj] >> 13);
        int pos = atomicAdd(&scur[row * 4 + p], 1);
        ssort[row * 32 + pos] = (u16)uu[jj];
    }
    __syncthreads();

    const int w  = tid >> 6;         // wave 0..3
    const int L  = tid & 63;
    const int kg = L >> 3;           // k-slot within bucket round
    const int co = L & 7;            // channel octet within quarter
    const u16* base = g_Yf + (size_t)b * N_ * COUT + q * 64 + co * 8;

    u16x8 mx[8];
#pragma unroll
    for (int i = 0; i < 8; ++i)
        mx[i] = (u16x8){0, 0, 0, 0, 0, 0, 0, 0};

#pragma unroll
    for (int p = 0; p < 3; ++p) {
#pragma unroll
        for (int h = 0; h < 2; ++h) {          // two row-quads per wave
            int mq[4], beg[4], end[4], last[4];
            u16x8 va[4], vb[4];
            // round 0: 4 independent loads (MLP=4)
#pragma unroll
            for (int s = 0; s < 4; ++s) {
                int ml = w * 8 + h * 4 + s;
                mq[s]  = ml < Mv ? ml : 0;     // dead rows redirect to row 0
                beg[s] = soff[mq[s] * 4 + p];
                end[s] = soff[mq[s] * 4 + p + 1];
                int lt = end[s] - 1;
                last[s] = lt > 0 ? lt : 0;
                int p0 = beg[s] + kg; p0 = p0 < last[s] ? p0 : last[s];
                unsigned i0 = (unsigned)ssort[mq[s] * 32 + p0];
                va[s] = *(const u16x8*)(base + (size_t)i0 * COUT);
            }
            // round 1 (duplicate-clamped when bucket <= 8)
#pragma unroll
            for (int s = 0; s < 4; ++s) {
                int p1 = beg[s] + 8 + kg; p1 = p1 < last[s] ? p1 : last[s];
                unsigned i1 = (unsigned)ssort[mq[s] * 32 + p1];
                vb[s] = *(const u16x8*)(base + (size_t)i1 * COUT);
            }
#pragma unroll
            for (int s = 0; s < 4; ++s)
                mx[h * 4 + s] = __builtin_elementwise_max(mx[h * 4 + s],
                    __builtin_elementwise_max(va[s], vb[s]));
            // rare tail: bucket > 16 (~2% of row-phases), wave-uniform trip
#pragma unroll
            for (int s = 0; s < 4; ++s) {
                for (int r = beg[s] + 16; r < end[s]; r += 8) {
                    int pp = r + kg; pp = pp < last[s] ? pp : last[s];
                    unsigned ii = (unsigned)ssort[mq[s] * 32 + pp];
                    u16x8 vv = *(const u16x8*)(base + (size_t)ii * COUT);
                    mx[h * 4 + s] = __builtin_elementwise_max(mx[h * 4 + s], vv);
                }
            }
        }
    }

    __syncthreads();   // all ssort/soff reads done; ymax aliases that storage

    // reduce across the 8 k-slots (lane bits 3,4,5)
#pragma unroll
    for (int i = 0; i < 8; ++i) {
        int ml = w * 8 + i;
        if (ml < Mv) {
            u16x8 m8 = mx[i];
#pragma unroll
            for (int mask = 8; mask <= 32; mask <<= 1) {
                int4 t = *(int4*)&m8;
                t.x = __shfl_xor(t.x, mask);
                t.y = __shfl_xor(t.y, mask);
                t.z = __shfl_xor(t.z, mask);
                t.w = __shfl_xor(t.w, mask);
                m8 = __builtin_elementwise_max(m8, *(u16x8*)&t);
            }
            if (kg == 0)   // one replicate writes 8 channels, 16B ds_write
                *(u16x8*)(ymax + ml * 400 + co * 8) = m8;
        }
    }
    __syncthreads();

    // transpose + bf16->fp32: out[b][q*64+c][m0..m0+31]
    int valid = Mv;
#pragma unroll
    for (int it = 0; it < 2; ++it) {
        int c  = it * 32 + (tid >> 3);   // local channel 0..63
        int mc = (tid & 7) << 2;
        if (mc + 4 <= valid) {
            float4 v;
            v.x = bf2f(ymax[(mc + 0) * 400 + c]);
            v.y = bf2f(ymax[(mc + 1) * 400 + c]);
            v.z = bf2f(ymax[(mc + 2) * 400 + c]);
            v.w = bf2f(ymax[(mc + 3) * 400 + c]);
            *(float4*)(out + (size_t)(b * COUT + q * 64 + c) * M_ + m0 + mc) = v;
        }
    }
}

extern "C" void kernel_launch(void* const* d_in, const int* in_sizes, int n_in,
                              void* d_out, int out_size, void* d_ws, size_t ws_size,
                              hipStream_t stream) {
    // inputs (all fp32 except neighbor_idx int32):
    // 0=query_xyz(unused) 1=support_xyz 2=features 3=neighbor_idx
    // 4=W1 5=b1 6=W2 7=b2. Output: fp32 [B][C_OUT][M].
    const float* xyz  = (const float*)d_in[1];
    const float* feat = (const float*)d_in[2];
    const int*   nbr  = (const int*)d_in[3];
    const float* W1   = (const float*)d_in[4];
    const float* b1   = (const float*)d_in[5];
    const float* W2   = (const float*)d_in[6];
    const float* b2   = (const float*)d_in[7];
    float* out = (float*)d_out;
    (void)d_ws; (void)ws_size;

    prep_weights<<<176, 256, 0, stream>>>(W1, W2);
    conv_fused<<<dim3(N_ / 64, B_), 256, 0, stream>>>(feat, xyz, b1, b2);
    gather_max<<<32 * QB_, 256, 0, stream>>>(nbr, out);   // 6016 blocks
}

// Round 7
// 249.240 us; speedup vs baseline: 4.9297x; 1.0159x over previous
//
#include <hip/hip_runtime.h>
#include <hip/hip_bf16.h>

typedef unsigned short u16;
typedef short s16x8 __attribute__((ext_vector_type(8)));
typedef float f32x4 __attribute__((ext_vector_type(4)));
typedef unsigned short u16x8 __attribute__((ext_vector_type(8)));

#define B_   8
#define N_   24000
#define M_   6000
#define K_   32
#define CIN  64
#define CMID 128
#define COUT 256
#define KP1  96    // 67 zero-padded to 3x32 for MFMA K-steps
#define QB_  188   // ceil(M/32) query-blocks per (batch, quarter) combo

// Static device globals — no ws_size assumption, graph-capture safe,
// fully rewritten on every call. Weights in MFMA fragment order.
__device__ __align__(16) u16 g_W1f[CMID * KP1];                 // 24.6 KB bf16
__device__ __align__(16) u16 g_W2f[COUT * CMID];                // 65.5 KB bf16
__device__ __align__(16) u16 g_Yf[(size_t)B_ * N_ * COUT];      // 98.3 MB bf16

__device__ __forceinline__ float bf2f(u16 u) {
    return __uint_as_float(((unsigned)u) << 16);
}
__device__ __forceinline__ u16 f2bf(float f) {  // fp32 -> bf16 RNE (scalar)
    unsigned u = __float_as_uint(f);
    u += 0x7FFFu + ((u >> 16) & 1u);
    return (u16)(u >> 16);
}
// packed fp32 pair -> 2x bf16 (RNE) in one u32; compiler emits
// v_cvt_pk_bf16_f32 (do NOT hand-write asm — m240). Bit-identical to f2bf.
__device__ __forceinline__ unsigned f2bf2(float lo, float hi) {
    __hip_bfloat162 h = __float22bfloat162_rn(make_float2(lo, hi));
    unsigned r;
    __builtin_memcpy(&r, &h, 4);
    return r;   // lo in bits[15:0], hi in bits[31:16]
}

// ---------------------------------------------------------------------------
// Kernel 0: convert fp32 weights to bf16 in fragment order. (unchanged)
// ---------------------------------------------------------------------------
__global__ void prep_weights(const float* __restrict__ W1,
                             const float* __restrict__ W2) {
    int t = blockIdx.x * 256 + threadIdx.x;   // 0..45055
    if (t < CMID * KP1) {                     // 12288 -> W1f
        int blk = t >> 9, off = t & 511;
        int L = off >> 3, j = off & 7;
        int ln = L & 15, quad = L >> 4;
        int w = blk / 6, r = blk % 6;
        int k0i = r >> 1, mt = r & 1;
        int row = w * 32 + mt * 16 + ln;
        int col = k0i * 32 + quad * 8 + j;
        g_W1f[t] = (col < 67) ? f2bf(W1[row * 67 + col]) : (u16)0;
    } else {                                  // 32768 -> W2f
        int i = t - CMID * KP1;
        int blk = i >> 9, off = i & 511;
        int L = off >> 3, j = off & 7;
        int ln = L & 15, quad = L >> 4;
        int w = blk >> 4, r = blk & 15;
        int k0i = r >> 2, mt = r & 3;
        int row = w * 64 + mt * 16 + ln;
        int col = k0i * 32 + quad * 8 + j;
        g_W2f[i] = f2bf(W2[row * 128 + col]);
    }
}

// ---------------------------------------------------------------------------
// Kernel 1: fused conv1+relu+conv2+relu, v3 (R14).
// R13 post-mortem: cvt_pk epilogues bought only ~3 us -> conv is NOT
// conversion-VALU-bound. Cycle budget (MFMA 2, LDS 18, VMEM 3, traffic 10 us)
// leaves ~70 us of EXPOSED LATENCY: 3000 short blocks x serial chain
// {stage (fresh 16KB HBM read, ~900 cyc) -> bar -> conv1 -> bar -> conv2 ->
// out} at ~3 blocks/CU = ~12 serial HBM exposures per CU. Also staging wrote
// 16 scalar ds_write_b16/thread all landing on banks {0,16} (row stride 104
// u16 => dword stride 16 mod 32) = ~16-way conflict.
// Fix (structure only; MFMA/layout/epilogues unchanged):
//  (1) 3 tiles/block (grid 125x8; 375=125x3): after staging tile t, PREFETCH
//      tile t+1's feat into 16 regs (coalesced b32) so HBM latency lands
//      under conv1+conv2+out (~3-4K cyc) instead of serially.
//  (2) staging v2: thread=(point p, ch-group cg); 16 coalesced b32 loads ->
//      8 cvt_pk -> 2 ds_write_b128 at Xs[p][cg*16]. Dword stride 52 == 20
//      mod 32 -> 8 lanes cover all 32 banks once; 64 lanes = 2/bank = free.
// Predict conv ~107 -> ~75-85 us; total 253 -> ~225-232.
// ---------------------------------------------------------------------------
__global__ __launch_bounds__(256) void conv_fused(
        const float* __restrict__ feat, const float* __restrict__ xyz,
        const float* __restrict__ b1,  const float* __restrict__ b2) {
    __shared__ __align__(16) u16 sm[16896];
    u16* Xs = sm;
    u16* Hs = sm + 6656;
    u16* Ys = sm;

    const int tid  = threadIdx.x;
    const int b    = blockIdx.y;
    const int w    = tid >> 6;
    const int L    = tid & 63;
    const int ln   = L & 15;
    const int quad = L >> 4;
    const int p    = L;          // point within tile (staging role)
    const int cg   = w;          // channel group 0..3 (staging role)

    const float* fbase = feat + (size_t)(b * CIN + cg * 16) * N_;

    float raw[16];
    float px = 0.f, py = 0.f, pz = 0.f;

    // prefetch tile 0
    {
        const int n0 = blockIdx.x * 192;
#pragma unroll
        for (int jj = 0; jj < 16; ++jj)
            raw[jj] = fbase[(size_t)jj * N_ + n0 + p];
        if (cg == 0) {
            const float* s = xyz + (size_t)(b * N_ + n0 + p) * 3;
            px = s[0]; py = s[1]; pz = s[2];
        }
    }

    for (int t = 0; t < 3; ++t) {
        const int n0 = blockIdx.x * 192 + t * 64;

        // ---- stage regs -> Xs (conflict-free b128 writes) ----
        {
            u16* dst = Xs + p * 104 + cg * 16;
            uint4 w0, w1;
            w0.x = f2bf2(raw[0],  raw[1]);  w0.y = f2bf2(raw[2],  raw[3]);
            w0.z = f2bf2(raw[4],  raw[5]);  w0.w = f2bf2(raw[6],  raw[7]);
            w1.x = f2bf2(raw[8],  raw[9]);  w1.y = f2bf2(raw[10], raw[11]);
            w1.z = f2bf2(raw[12], raw[13]); w1.w = f2bf2(raw[14], raw[15]);
            *(uint4*)dst = w0;
            *(uint4*)(dst + 8) = w1;
            if (cg == 0) {   // channels 64..95: xyz + zero pad
                u16* xr = Xs + p * 104 + 64;
                uint4 z4; z4.x = f2bf2(px, py); z4.y = f2bf2(pz, 0.f);
                z4.z = 0u; z4.w = 0u;
                uint4 zz; zz.x = zz.y = zz.z = zz.w = 0u;
                *(uint4*)xr = z4;
                *(uint4*)(xr + 8)  = zz;
                *(uint4*)(xr + 16) = zz;
                *(uint4*)(xr + 24) = zz;
            }
        }
        __syncthreads();

        // ---- prefetch next tile (lands under conv1+conv2+out) ----
        if (t < 2) {
            const int n1 = n0 + 64;
#pragma unroll
            for (int jj = 0; jj < 16; ++jj)
                raw[jj] = fbase[(size_t)jj * N_ + n1 + p];
            if (cg == 0) {
                const float* s = xyz + (size_t)(b * N_ + n1 + p) * 3;
                px = s[0]; py = s[1]; pz = s[2];
            }
        }

        // ---- conv1 ----
        f32x4 acc1[2][4];
#pragma unroll
        for (int mt = 0; mt < 2; ++mt)
#pragma unroll
            for (int nt = 0; nt < 4; ++nt) {
                f32x4 zz = {0.f, 0.f, 0.f, 0.f};
                acc1[mt][nt] = zz;
            }
#pragma unroll
        for (int k0i = 0; k0i < 3; ++k0i) {
            s16x8 af[2], xf[4];
#pragma unroll
            for (int mt = 0; mt < 2; ++mt)
                af[mt] = *(const s16x8*)(g_W1f + (((w * 3 + k0i) * 2 + mt) << 9) + L * 8);
#pragma unroll
            for (int nt = 0; nt < 4; ++nt)
                xf[nt] = *(const s16x8*)(Xs + (nt * 16 + ln) * 104 + k0i * 32 + quad * 8);
#pragma unroll
            for (int mt = 0; mt < 2; ++mt)
#pragma unroll
                for (int nt = 0; nt < 4; ++nt)
                    acc1[mt][nt] = __builtin_amdgcn_mfma_f32_16x16x32_bf16(
                        af[mt], xf[nt], acc1[mt][nt], 0, 0, 0);
        }
#pragma unroll
        for (int mt = 0; mt < 2; ++mt) {
            int m0 = w * 32 + mt * 16 + quad * 4;
            float4 bv = *(const float4*)(b1 + m0);
#pragma unroll
            for (int nt = 0; nt < 4; ++nt) {
                int pp = nt * 16 + ln;
                uint2 hv;
                hv.x = f2bf2(fmaxf(acc1[mt][nt][0] + bv.x, 0.f),
                             fmaxf(acc1[mt][nt][1] + bv.y, 0.f));
                hv.y = f2bf2(fmaxf(acc1[mt][nt][2] + bv.z, 0.f),
                             fmaxf(acc1[mt][nt][3] + bv.w, 0.f));
                *(uint2*)(Hs + pp * 136 + m0) = hv;
            }
        }
        __syncthreads();

        // ---- conv2 ----
        f32x4 acc2[4][4];
#pragma unroll
        for (int mt = 0; mt < 4; ++mt)
#pragma unroll
            for (int nt = 0; nt < 4; ++nt) {
                f32x4 zz = {0.f, 0.f, 0.f, 0.f};
                acc2[mt][nt] = zz;
            }
#pragma unroll
        for (int k0i = 0; k0i < 4; ++k0i) {
            s16x8 af[4], hf[4];
#pragma unroll
            for (int mt = 0; mt < 4; ++mt)
                af[mt] = *(const s16x8*)(g_W2f + (((w * 4 + k0i) * 4 + mt) << 9) + L * 8);
#pragma unroll
            for (int nt = 0; nt < 4; ++nt)
                hf[nt] = *(const s16x8*)(Hs + (nt * 16 + ln) * 136 + k0i * 32 + quad * 8);
#pragma unroll
            for (int mt = 0; mt < 4; ++mt)
#pragma unroll
                for (int nt = 0; nt < 4; ++nt)
                    acc2[mt][nt] = __builtin_amdgcn_mfma_f32_16x16x32_bf16(
                        af[mt], hf[nt], acc2[mt][nt], 0, 0, 0);
        }
        __syncthreads();   // conv2's Hs reads done; Ys (aliases Xs+Hs) writable

        // ---- epilogue 2 -> Ys ----
#pragma unroll
        for (int mt = 0; mt < 4; ++mt) {
            int c0 = w * 64 + mt * 16 + quad * 4;
            float4 bv = *(const float4*)(b2 + c0);
#pragma unroll
            for (int nt = 0; nt < 4; ++nt) {
                int pp = nt * 16 + ln;
                uint2 yv;
                yv.x = f2bf2(fmaxf(acc2[mt][nt][0] + bv.x, 0.f),
                             fmaxf(acc2[mt][nt][1] + bv.y, 0.f));
                yv.y = f2bf2(fmaxf(acc2[mt][nt][2] + bv.z, 0.f),
                             fmaxf(acc2[mt][nt][3] + bv.w, 0.f));
                *(uint2*)(Ys + pp * 264 + c0) = yv;
            }
        }
        __syncthreads();

        // ---- Ys -> g_Yf (coalesced dwordx4) ----
        u16* dstY = g_Yf + ((size_t)b * N_ + n0) * COUT;
#pragma unroll
        for (int i = 0; i < 8; ++i) {
            int g = i * 256 + tid;
            int pp = g >> 5, c16 = g & 31;
            *(uint4*)(dstY + (size_t)pp * COUT + c16 * 8) =
                *(const uint4*)(Ys + pp * 264 + c16 * 8);
        }
        if (t < 2) __syncthreads();   // Ys reads done before next Xs write
    }
}

// ---------------------------------------------------------------------------
// Kernel 2: gather + max — measured-best R2 bucket-sorted version, UNCHANGED
// (control: dur ~107.5 us, FETCH ~306 MB, VALU ~32%). L2-locality program
// CLOSED after 5 falsified schemes (R5 hard-barrier test: even a single
// resident 3.07 MB slab is evicted by streaming write/index traffic).
// ---------------------------------------------------------------------------
__global__ __launch_bounds__(256) void gather_max(
        const int* __restrict__ nbr, float* __restrict__ out) {
    __shared__ __align__(16) u16 smem[32 * 400];          // 25.6 KB union
    int* sidx  = (int*)smem;                              // [1024] bytes 0..4095
    u16* ssort = smem + 2048;                             // [1024] bytes 4096..6143
    int* soff  = (int*)(smem + 3072);                     // [128]  bytes 6144..6655
    int* scur  = (int*)(smem + 3328);                     // [128]  bytes 6656..7167
    u16* ymax  = smem;                                    // [32*400] post-gather

    const int tid = threadIdx.x;
    const int l   = blockIdx.x;
    const int xcd = l & 7;
    const int j   = l >> 3;          // 0..751
    const int cw  = j / QB_;         // combo-within-XCD 0..3
    const int qb  = j % QB_;         // query-block 0..187
    const int combo = cw * 8 + xcd;  // 0..31
    const int b   = combo >> 2;
    const int q   = combo & 3;       // channel quarter (64 ch)
    const int m0  = qb * 32;
    const int row = tid >> 3;        // row owning this thread's 4 staged ints
    const int Mv0 = M_ - m0;
    const int Mv  = Mv0 < 32 ? Mv0 : 32;   // valid rows this block (16 or 32)

    // stage neighbor indices (32 queries x 32 k) + zero bucket counters
    if (row < Mv)
        *(int4*)(sidx + tid * 4) =
            *(const int4*)(nbr + ((size_t)b * M_ + m0) * K_ + tid * 4);
    if (tid < 128) scur[tid] = 0;
    __syncthreads();

    // pass 1: per-row phase histogram (phases 0,1 only; 2 is implied)
    unsigned uu[4];
#pragma unroll
    for (int jj = 0; jj < 4; ++jj) {
        unsigned u = (unsigned)sidx[tid * 4 + jj];
        u = u < (unsigned)N_ ? u : 0u;     // defensive clamp (also garbage rows)
        uu[jj] = u;
        int pp = (int)(u >> 13);           // 0:[0,8192) 1:[8192,16384) 2:rest
        if (pp < 2) atomicAdd(&scur[row * 4 + pp], 1);
    }
    __syncthreads();

    // prefix: bucket offsets; reset cursors to bucket starts
    if (tid < 32) {
        int c0 = scur[tid * 4 + 0], c1 = scur[tid * 4 + 1];
        soff[tid * 4 + 0] = 0;
        soff[tid * 4 + 1] = c0;
        soff[tid * 4 + 2] = c0 + c1;
        soff[tid * 4 + 3] = 32;
        scur[tid * 4 + 0] = 0;
        scur[tid * 4 + 1] = c0;
        scur[tid * 4 + 2] = c0 + c1;
    }
    __syncthreads();

    // pass 2: place indices into phase buckets (order within bucket arbitrary)
#pragma unroll
    for (int jj = 0; jj < 4; ++jj) {
        int pp = (int)(uu[jj] >> 13);
        int pos = atomicAdd(&scur[row * 4 + pp], 1);
        ssort[row * 32 + pos] = (u16)uu[jj];
    }
    __syncthreads();

    const int w  = tid >> 6;         // wave 0..3
    const int L  = tid & 63;
    const int kg = L >> 3;           // k-slot within bucket round
    const int co = L & 7;            // channel octet within quarter
    const u16* base = g_Yf + (size_t)b * N_ * COUT + q * 64 + co * 8;

    u16x8 mx[8];
#pragma unroll
    for (int i = 0; i < 8; ++i)
        mx[i] = (u16x8){0, 0, 0, 0, 0, 0, 0, 0};

#pragma unroll
    for (int p = 0; p < 3; ++p) {
#pragma unroll
        for (int h = 0; h < 2; ++h) {          // two row-quads per wave
            int mq[4], beg[4], end[4], last[4];
            u16x8 va[4], vb[4];
            // round 0: 4 independent loads (MLP=4)
#pragma unroll
            for (int s = 0; s < 4; ++s) {
                int ml = w * 8 + h * 4 + s;
                mq[s]  = ml < Mv ? ml : 0;     // dead rows redirect to row 0
                beg[s] = soff[mq[s] * 4 + p];
                end[s] = soff[mq[s] * 4 + p + 1];
                int lt = end[s] - 1;
                last[s] = lt > 0 ? lt : 0;
                int p0 = beg[s] + kg; p0 = p0 < last[s] ? p0 : last[s];
                unsigned i0 = (unsigned)ssort[mq[s] * 32 + p0];
                va[s] = *(const u16x8*)(base + (size_t)i0 * COUT);
            }
            // round 1 (duplicate-clamped when bucket <= 8)
#pragma unroll
            for (int s = 0; s < 4; ++s) {
                int p1 = beg[s] + 8 + kg; p1 = p1 < last[s] ? p1 : last[s];
                unsigned i1 = (unsigned)ssort[mq[s] * 32 + p1];
                vb[s] = *(const u16x8*)(base + (size_t)i1 * COUT);
            }
#pragma unroll
            for (int s = 0; s < 4; ++s)
                mx[h * 4 + s] = __builtin_elementwise_max(mx[h * 4 + s],
                    __builtin_elementwise_max(va[s], vb[s]));
            // rare tail: bucket > 16 (~2% of row-phases), wave-uniform trip
#pragma unroll
            for (int s = 0; s < 4; ++s) {
                for (int r = beg[s] + 16; r < end[s]; r += 8) {
                    int pq = r + kg; pq = pq < last[s] ? pq : last[s];
                    unsigned ii = (unsigned)ssort[mq[s] * 32 + pq];
                    u16x8 vv = *(const u16x8*)(base + (size_t)ii * COUT);
                    mx[h * 4 + s] = __builtin_elementwise_max(mx[h * 4 + s], vv);
                }
            }
        }
    }

    __syncthreads();   // all ssort/soff reads done; ymax aliases that storage

    // reduce across the 8 k-slots (lane bits 3,4,5)
#pragma unroll
    for (int i = 0; i < 8; ++i) {
        int ml = w * 8 + i;
        if (ml < Mv) {
            u16x8 m8 = mx[i];
#pragma unroll
            for (int mask = 8; mask <= 32; mask <<= 1) {
                int4 t = *(int4*)&m8;
                t.x = __shfl_xor(t.x, mask);
                t.y = __shfl_xor(t.y, mask);
                t.z = __shfl_xor(t.z, mask);
                t.w = __shfl_xor(t.w, mask);
                m8 = __builtin_elementwise_max(m8, *(u16x8*)&t);
            }
            if (kg == 0)   // one replicate writes 8 channels, 16B ds_write
                *(u16x8*)(ymax + ml * 400 + co * 8) = m8;
        }
    }
    __syncthreads();

    // transpose + bf16->fp32: out[b][q*64+c][m0..m0+31]
    int valid = Mv;
#pragma unroll
    for (int it = 0; it < 2; ++it) {
        int c  = it * 32 + (tid >> 3);   // local channel 0..63
        int mc = (tid & 7) << 2;
        if (mc + 4 <= valid) {
            float4 v;
            v.x = bf2f(ymax[(mc + 0) * 400 + c]);
            v.y = bf2f(ymax[(mc + 1) * 400 + c]);
            v.z = bf2f(ymax[(mc + 2) * 400 + c]);
            v.w = bf2f(ymax[(mc + 3) * 400 + c]);
            *(float4*)(out + (size_t)(b * COUT + q * 64 + c) * M_ + m0 + mc) = v;
        }
    }
}

extern "C" void kernel_launch(void* const* d_in, const int* in_sizes, int n_in,
                              void* d_out, int out_size, void* d_ws, size_t ws_size,
                              hipStream_t stream) {
    // inputs (all fp32 except neighbor_idx int32):
    // 0=query_xyz(unused) 1=support_xyz 2=features 3=neighbor_idx
    // 4=W1 5=b1 6=W2 7=b2. Output: fp32 [B][C_OUT][M].
    const float* xyz  = (const float*)d_in[1];
    const float* feat = (const float*)d_in[2];
    const int*   nbr  = (const int*)d_in[3];
    const float* W1   = (const float*)d_in[4];
    const float* b1   = (const float*)d_in[5];
    const float* W2   = (const float*)d_in[6];
    const float* b2   = (const float*)d_in[7];
    float* out = (float*)d_out;
    (void)d_ws; (void)ws_size;

    prep_weights<<<176, 256, 0, stream>>>(W1, W2);
    conv_fused<<<dim3(125, B_), 256, 0, stream>>>(feat, xyz, b1, b2);
    gather_max<<<32 * QB_, 256, 0, stream>>>(nbr, out);   // 6016 blocks
}